// Round 1
// baseline (959.509 us; speedup 1.0000x reference)
//
#include <hip/hip_runtime.h>
#include <hip/hip_bf16.h>
#include <math.h>

// Problem constants
#define NTOK 16384   // B*N = 4*4096
#define DM   1024
#define NQKV 3072
#define DFF  4096

typedef __bf16 bf16;
typedef __bf16 bf16x8 __attribute__((ext_vector_type(8)));
typedef float  f32x4  __attribute__((ext_vector_type(4)));

__device__ __forceinline__ void gload_lds16(const bf16* g, bf16* l) {
  __builtin_amdgcn_global_load_lds((const __attribute__((address_space(1))) void*)g,
                                   (__attribute__((address_space(3))) void*)l,
                                   16, 0, 0);
}

// ---------------- weight transpose + bf16 convert: src[K][N] fp32 -> dst[N][K] bf16 ----
__global__ __launch_bounds__(256)
void transpose_cvt(const float* __restrict__ src, bf16* __restrict__ dst, int K, int N)
{
  __shared__ float t[32][33];
  const int tx = threadIdx.x & 31, ty = threadIdx.x >> 5;
  const int n0 = blockIdx.x * 32, k0 = blockIdx.y * 32;
#pragma unroll
  for (int i = 0; i < 4; ++i)
    t[ty + 8*i][tx] = src[(size_t)(k0 + ty + 8*i) * N + n0 + tx];
  __syncthreads();
#pragma unroll
  for (int i = 0; i < 4; ++i)
    dst[(size_t)(n0 + ty + 8*i) * K + k0 + tx] = (bf16)t[tx][ty + 8*i];
}

__global__ void concat_bias(const float* __restrict__ bq, const float* __restrict__ bk,
                            const float* __restrict__ bv, float* __restrict__ o)
{
  int i = blockIdx.x * 256 + threadIdx.x;
  o[i] = (i < 1024) ? bq[i] : (i < 2048 ? bk[i - 1024] : bv[i - 2048]);
}

// ---------------- LayerNorm 1: x fp32 -> h bf16 --------------------------------------
__global__ __launch_bounds__(256)
void ln1_kernel(const float* __restrict__ x, const float* __restrict__ gamma,
                bf16* __restrict__ out)
{
  __shared__ float2 red[4];
  const int row = blockIdx.x, tid = threadIdx.x;
  const float4 v = ((const float4*)(x + (size_t)row * DM))[tid];
  float s  = v.x + v.y + v.z + v.w;
  float s2 = v.x*v.x + v.y*v.y + v.z*v.z + v.w*v.w;
#pragma unroll
  for (int m = 32; m >= 1; m >>= 1) { s += __shfl_xor(s, m); s2 += __shfl_xor(s2, m); }
  if ((tid & 63) == 0) red[tid >> 6] = make_float2(s, s2);
  __syncthreads();
  float S  = red[0].x + red[1].x + red[2].x + red[3].x;
  float S2 = red[0].y + red[1].y + red[2].y + red[3].y;
  const float mean = S * (1.0f / DM);
  const float var  = S2 * (1.0f / DM) - mean * mean;
  const float rs   = rsqrtf(var + 1e-5f);
  const float4 g = ((const float4*)gamma)[tid];
  union { bf16 b[4]; uint2 u; } o;
  o.b[0] = (bf16)((v.x - mean) * rs * g.x);
  o.b[1] = (bf16)((v.y - mean) * rs * g.y);
  o.b[2] = (bf16)((v.z - mean) * rs * g.z);
  o.b[3] = (bf16)((v.w - mean) * rs * g.w);
  *(uint2*)(out + (size_t)row * DM + tid * 4) = o.u;
}

// ---------------- LayerNorm 2 (double LN): xnew fp32 -> h2 bf16 ----------------------
__global__ __launch_bounds__(256)
void ln2_kernel(const float* __restrict__ x, const float* __restrict__ gamma,
                const float* __restrict__ ffg, const float* __restrict__ ffb,
                bf16* __restrict__ out)
{
  __shared__ float2 red[4];
  const int row = blockIdx.x, tid = threadIdx.x;
  const float4 v = ((const float4*)(x + (size_t)row * DM))[tid];
  float s  = v.x + v.y + v.z + v.w;
  float s2 = v.x*v.x + v.y*v.y + v.z*v.z + v.w*v.w;
#pragma unroll
  for (int m = 32; m >= 1; m >>= 1) { s += __shfl_xor(s, m); s2 += __shfl_xor(s2, m); }
  if ((tid & 63) == 0) red[tid >> 6] = make_float2(s, s2);
  __syncthreads();
  float S  = red[0].x + red[1].x + red[2].x + red[3].x;
  float S2 = red[0].y + red[1].y + red[2].y + red[3].y;
  float mean = S * (1.0f / DM);
  float var  = S2 * (1.0f / DM) - mean * mean;
  float rs   = rsqrtf(var + 1e-5f);
  const float4 g = ((const float4*)gamma)[tid];
  float y0 = (v.x - mean) * rs * g.x;
  float y1 = (v.y - mean) * rs * g.y;
  float y2 = (v.z - mean) * rs * g.z;
  float y3 = (v.w - mean) * rs * g.w;
  __syncthreads();  // red[] reuse
  s  = y0 + y1 + y2 + y3;
  s2 = y0*y0 + y1*y1 + y2*y2 + y3*y3;
#pragma unroll
  for (int m = 32; m >= 1; m >>= 1) { s += __shfl_xor(s, m); s2 += __shfl_xor(s2, m); }
  if ((tid & 63) == 0) red[tid >> 6] = make_float2(s, s2);
  __syncthreads();
  S  = red[0].x + red[1].x + red[2].x + red[3].x;
  S2 = red[0].y + red[1].y + red[2].y + red[3].y;
  mean = S * (1.0f / DM);
  var  = S2 * (1.0f / DM) - mean * mean;
  rs   = rsqrtf(var + 1e-5f);
  const float4 a = ((const float4*)ffg)[tid];
  const float4 bb = ((const float4*)ffb)[tid];
  union { bf16 b[4]; uint2 u; } o;
  o.b[0] = (bf16)((y0 - mean) * rs * a.x + bb.x);
  o.b[1] = (bf16)((y1 - mean) * rs * a.y + bb.y);
  o.b[2] = (bf16)((y2 - mean) * rs * a.z + bb.z);
  o.b[3] = (bf16)((y3 - mean) * rs * a.w + bb.w);
  *(uint2*)(out + (size_t)row * DM + tid * 4) = o.u;
}

// ---------------- GEMM: C[M x N] = A[M x K](bf16,lda) @ Bt[N x K]^T + bias -----------
// EPI 0: out bf16 = acc + bias
// EPI 1: out fp32 = acc + bias + res (residual)
// EPI 2: out bf16 = gelu_exact(acc + bias)
template<int EPI>
__global__ __launch_bounds__(256)
void gemm_bt(const bf16* __restrict__ A, long lda,
             const bf16* __restrict__ Bt,
             const float* __restrict__ bias,
             const float* res, long ldres,
             void* Cout, long ldc, int K)
{
  __shared__ bf16 As[128 * 64];
  __shared__ bf16 Bs[128 * 64];
  const int tid  = threadIdx.x;
  const int lane = tid & 63;
  const int wave = tid >> 6;
  const int wr = wave >> 1, wc = wave & 1;
  const int l16 = lane & 15, lg = lane >> 4;
  const long row0 = (long)blockIdx.x * 128;
  const long col0 = (long)blockIdx.y * 128;

  f32x4 acc[4][4] = {};
  const int sr   = tid >> 3;        // 0..31 row within 32-row staging chunk
  const int scol = (tid & 7) * 8;   // 0..56

  for (int k0 = 0; k0 < K; k0 += 64) {
    __syncthreads();
#pragma unroll
    for (int it = 0; it < 4; ++it) {
      int r = it * 32 + sr;
      gload_lds16(&A [(row0 + r) * lda + k0 + scol], &As[r * 64 + scol]);
      gload_lds16(&Bt[(col0 + r) * (long)K + k0 + scol], &Bs[r * 64 + scol]);
    }
    __syncthreads();
#pragma unroll
    for (int kk = 0; kk < 64; kk += 32) {
      bf16x8 af[4], bfr[4];
#pragma unroll
      for (int i = 0; i < 4; ++i)
        af[i] = *(const bf16x8*)&As[(wr * 64 + i * 16 + l16) * 64 + kk + lg * 8];
#pragma unroll
      for (int j = 0; j < 4; ++j)
        bfr[j] = *(const bf16x8*)&Bs[(wc * 64 + j * 16 + l16) * 64 + kk + lg * 8];
#pragma unroll
      for (int i = 0; i < 4; ++i)
#pragma unroll
        for (int j = 0; j < 4; ++j)
          acc[i][j] = __builtin_amdgcn_mfma_f32_16x16x32_bf16(af[i], bfr[j], acc[i][j], 0, 0, 0);
    }
  }

  const long cR = row0 + wr * 64;
  const long cC = col0 + wc * 64;
#pragma unroll
  for (int j = 0; j < 4; ++j) {
    const long n = cC + j * 16 + l16;
    const float bv = bias[n];
#pragma unroll
    for (int i = 0; i < 4; ++i) {
#pragma unroll
      for (int r = 0; r < 4; ++r) {
        const long m = cR + i * 16 + lg * 4 + r;
        float v = acc[i][j][r] + bv;
        if constexpr (EPI == 0) {
          ((bf16*)Cout)[m * ldc + n] = (bf16)v;
        } else if constexpr (EPI == 1) {
          ((float*)Cout)[m * ldc + n] = v + res[m * ldres + n];
        } else {
          float gl = 0.5f * v * (1.0f + erff(v * 0.70710678118654752f));
          ((bf16*)Cout)[m * ldc + n] = (bf16)gl;
        }
      }
    }
  }
}

// ---------------- dilated attention: one wave per (b, g, h) --------------------------
// qkv layout: [NTOK][3072] bf16, cols 0..1023=Q, 1024..2047=K, 2048..3071=V
// Output overwrites the Q columns in place (only this block touches rows (b,g), cols h*64..h*64+63 of Q).
__global__ __launch_bounds__(64)
void attn_kernel(bf16* qkv)
{
  __shared__ bf16 Plds[32 * 32];
  __shared__ bf16 vT[64 * 32];
  const int blk = blockIdx.x;
  const int h = blk & 15;
  const int g = (blk >> 4) & 63;
  const int b = blk >> 10;
  const int par = h & 1;
  const int lane = threadIdx.x;
  const int l16 = lane & 15, lg = lane >> 4;
  const long base = ((long)b * 4096 + g * 64) * NQKV;

  // Q / K fragments straight from global (contiguous 8 bf16 along K-dim)
  bf16x8 qf[2][2], kf[2][2];
#pragma unroll
  for (int mb = 0; mb < 2; ++mb) {
    const int s = par + 2 * (mb * 16 + l16);
    const bf16* qrow = qkv + base + (long)s * NQKV + h * 64;
#pragma unroll
    for (int kk = 0; kk < 2; ++kk) {
      qf[mb][kk] = *(const bf16x8*)(qrow + kk * 32 + lg * 8);
      kf[mb][kk] = *(const bf16x8*)(qrow + 1024 + kk * 32 + lg * 8);
    }
  }

  // stage V transposed: vT[dh][kr] = V[s(kr)][h*64+dh]
#pragma unroll
  for (int it = 0; it < 4; ++it) {
    const int kr  = it * 8 + (lane >> 3);
    const int dh0 = (lane & 7) * 8;
    const int s = par + 2 * kr;
    union { uint4 u; bf16 e[8]; } vv;
    vv.u = *(const uint4*)(qkv + base + (long)s * NQKV + 2048 + h * 64 + dh0);
#pragma unroll
    for (int j = 0; j < 8; ++j)
      vT[(dh0 + j) * 32 + kr] = vv.e[j];
  }

  // scores = Q Kt * 0.125 (32x32)
  f32x4 sc[2][2] = {};
#pragma unroll
  for (int mb = 0; mb < 2; ++mb)
#pragma unroll
    for (int nb = 0; nb < 2; ++nb)
#pragma unroll
      for (int kk = 0; kk < 2; ++kk)
        sc[mb][nb] = __builtin_amdgcn_mfma_f32_16x16x32_bf16(qf[mb][kk], kf[nb][kk], sc[mb][nb], 0, 0, 0);

  // row softmax (rows spread over 16-lane groups sharing lg)
  float pr[2][2][4];
#pragma unroll
  for (int mb = 0; mb < 2; ++mb)
#pragma unroll
    for (int r = 0; r < 4; ++r) {
      float a0 = sc[mb][0][r] * 0.125f, a1 = sc[mb][1][r] * 0.125f;
      float mx = fmaxf(a0, a1);
#pragma unroll
      for (int msk = 8; msk >= 1; msk >>= 1) mx = fmaxf(mx, __shfl_xor(mx, msk));
      float e0 = expf(a0 - mx), e1 = expf(a1 - mx);
      float sm = e0 + e1;
#pragma unroll
      for (int msk = 8; msk >= 1; msk >>= 1) sm += __shfl_xor(sm, msk);
      float inv = 1.0f / sm;
      pr[mb][0][r] = e0 * inv;
      pr[mb][1][r] = e1 * inv;
    }

  __syncthreads();  // vT writes visible
#pragma unroll
  for (int mb = 0; mb < 2; ++mb)
#pragma unroll
    for (int nb = 0; nb < 2; ++nb)
#pragma unroll
      for (int r = 0; r < 4; ++r)
        Plds[(mb * 16 + lg * 4 + r) * 32 + nb * 16 + l16] = (bf16)pr[mb][nb][r];
  __syncthreads();

  // O = P @ V  (32 x 64)
  bf16x8 pa[2], vb[4];
#pragma unroll
  for (int mb = 0; mb < 2; ++mb)
    pa[mb] = *(const bf16x8*)&Plds[(mb * 16 + l16) * 32 + lg * 8];
#pragma unroll
  for (int nb = 0; nb < 4; ++nb)
    vb[nb] = *(const bf16x8*)&vT[(nb * 16 + l16) * 32 + lg * 8];
  f32x4 oc[2][4] = {};
#pragma unroll
  for (int mb = 0; mb < 2; ++mb)
#pragma unroll
    for (int nb = 0; nb < 4; ++nb)
      oc[mb][nb] = __builtin_amdgcn_mfma_f32_16x16x32_bf16(pa[mb], vb[nb], oc[mb][nb], 0, 0, 0);

  // write O into the Q columns (rows parity=par), zeros into other-parity rows
#pragma unroll
  for (int mb = 0; mb < 2; ++mb)
#pragma unroll
    for (int nb = 0; nb < 4; ++nb)
#pragma unroll
      for (int r = 0; r < 4; ++r) {
        const int m = mb * 16 + lg * 4 + r;
        const int s = par + 2 * m;
        qkv[base + (long)s * NQKV + h * 64 + nb * 16 + l16] = (bf16)oc[mb][nb][r];
      }
  const uint4 z = make_uint4(0, 0, 0, 0);
#pragma unroll
  for (int it = 0; it < 4; ++it) {
    const int r2 = it * 8 + (lane >> 3);
    const int s = (1 - par) + 2 * r2;
    *(uint4*)(qkv + base + (long)s * NQKV + h * 64 + (lane & 7) * 8) = z;
  }
}

// ---------------- host-side orchestration --------------------------------------------
extern "C" void kernel_launch(void* const* d_in, const int* in_sizes, int n_in,
                              void* d_out, int out_size, void* d_ws, size_t ws_size,
                              hipStream_t stream)
{
  const float* x     = (const float*)d_in[0];
  const float* gamma = (const float*)d_in[1];
  const float* wq = (const float*)d_in[2];  const float* bq = (const float*)d_in[3];
  const float* wk = (const float*)d_in[4];  const float* bk = (const float*)d_in[5];
  const float* wv = (const float*)d_in[6];  const float* bv = (const float*)d_in[7];
  const float* wo = (const float*)d_in[8];  const float* bo = (const float*)d_in[9];
  const float* ffg = (const float*)d_in[10]; const float* ffb = (const float*)d_in[11];
  const float* w1 = (const float*)d_in[12]; const float* b1 = (const float*)d_in[13];
  const float* w2 = (const float*)d_in[14]; const float* b2 = (const float*)d_in[15];

  char* p = (char*)d_ws;
  bf16* Wqkv_t = (bf16*)p; p += (size_t)NQKV * DM * 2;        // 6 MB  [3072][1024]
  bf16* Wo_t   = (bf16*)p; p += (size_t)DM * DM * 2;          // 2 MB  [1024][1024]
  bf16* W1_t   = (bf16*)p; p += (size_t)DFF * DM * 2;         // 8 MB  [4096][1024]
  bf16* W2_t   = (bf16*)p; p += (size_t)DM * DFF * 2;         // 8 MB  [1024][4096]
  float* bqkv  = (float*)p; p += (size_t)NQKV * 4;            // 12 KB
  bf16* hbuf   = (bf16*)p; p += (size_t)NTOK * DM * 2;        // 32 MB (h, then h2)
  bf16* qkv    = (bf16*)p; p += (size_t)NTOK * DFF * 2;       // 128 MB (qkv, then g1)
  float* xnew  = (float*)d_out;                               // x+attn lives in d_out

  dim3 b256(256);
  // weights -> bf16 transposed
  transpose_cvt<<<dim3(32, 32),  b256, 0, stream>>>(wq, Wqkv_t,              DM, DM);
  transpose_cvt<<<dim3(32, 32),  b256, 0, stream>>>(wk, Wqkv_t + 1024 * 1024, DM, DM);
  transpose_cvt<<<dim3(32, 32),  b256, 0, stream>>>(wv, Wqkv_t + 2048 * 1024, DM, DM);
  transpose_cvt<<<dim3(32, 32),  b256, 0, stream>>>(wo, Wo_t, DM, DM);
  transpose_cvt<<<dim3(128, 32), b256, 0, stream>>>(w1, W1_t, DM, DFF);
  transpose_cvt<<<dim3(32, 128), b256, 0, stream>>>(w2, W2_t, DFF, DM);
  concat_bias<<<12, b256, 0, stream>>>(bq, bk, bv, bqkv);

  // LN1: x -> h (bf16)
  ln1_kernel<<<NTOK, b256, 0, stream>>>(x, gamma, hbuf);

  // QKV GEMM: h @ [wq|wk|wv] -> qkv bf16 [16384][3072]
  gemm_bt<0><<<dim3(NTOK / 128, NQKV / 128), b256, 0, stream>>>(
      hbuf, DM, Wqkv_t, bqkv, nullptr, 0, qkv, NQKV, DM);

  // dilated attention, writes result into Q columns of qkv
  attn_kernel<<<4096, dim3(64), 0, stream>>>(qkv);

  // WO GEMM + residual: attn(lda=3072) @ wo + bo + x -> xnew fp32 (d_out)
  gemm_bt<1><<<dim3(NTOK / 128, DM / 128), b256, 0, stream>>>(
      qkv, NQKV, Wo_t, bo, x, DM, xnew, DM, DM);

  // LN2 (double LN): xnew -> h2 bf16
  ln2_kernel<<<NTOK, b256, 0, stream>>>(xnew, gamma, ffg, ffb, hbuf);

  // FFN1 + GELU: h2 @ w1 + b1 -> g1 bf16 [16384][4096] (reuses qkv buffer)
  gemm_bt<2><<<dim3(NTOK / 128, DFF / 128), b256, 0, stream>>>(
      hbuf, DM, W1_t, b1, nullptr, 0, qkv, DFF, DM);

  // FFN2 + residual: g1 @ w2 + b2 + xnew -> d_out fp32
  gemm_bt<1><<<dim3(NTOK / 128, DM / 128), b256, 0, stream>>>(
      qkv, DFF, W2_t, b2, xnew, DM, (float*)d_out, DM, DFF);
}

// Round 2
// 690.468 us; speedup vs baseline: 1.3897x; 1.3897x over previous
//
#include <hip/hip_runtime.h>
#include <hip/hip_bf16.h>
#include <math.h>

// Problem constants
#define NTOK 16384   // B*N = 4*4096
#define DM   1024
#define NQKV 3072
#define DFF  4096

typedef __bf16 bf16;
typedef __bf16 bf16x8 __attribute__((ext_vector_type(8)));
typedef float  f32x4  __attribute__((ext_vector_type(4)));

__device__ __forceinline__ void gload_lds16(const bf16* g, bf16* l) {
  __builtin_amdgcn_global_load_lds((const __attribute__((address_space(1))) void*)g,
                                   (__attribute__((address_space(3))) void*)l,
                                   16, 0, 0);
}

#define BAR()   asm volatile("s_barrier" ::: "memory")
#define LGKM0() asm volatile("s_waitcnt lgkmcnt(0)" ::: "memory")
#define VMW4()  asm volatile("s_waitcnt vmcnt(4)" ::: "memory")
#define VMW0()  asm volatile("s_waitcnt vmcnt(0)" ::: "memory")

// ---------------- weight transpose + bf16 convert: src[K][N] fp32 -> dst[N][K] bf16 ----
__global__ __launch_bounds__(256)
void transpose_cvt(const float* __restrict__ src, bf16* __restrict__ dst, int K, int N)
{
  __shared__ float t[32][33];
  const int tx = threadIdx.x & 31, ty = threadIdx.x >> 5;
  const int n0 = blockIdx.x * 32, k0 = blockIdx.y * 32;
#pragma unroll
  for (int i = 0; i < 4; ++i)
    t[ty + 8*i][tx] = src[(size_t)(k0 + ty + 8*i) * N + n0 + tx];
  __syncthreads();
#pragma unroll
  for (int i = 0; i < 4; ++i)
    dst[(size_t)(n0 + ty + 8*i) * K + k0 + tx] = (bf16)t[tx][ty + 8*i];
}

__global__ void concat_bias(const float* __restrict__ bq, const float* __restrict__ bk,
                            const float* __restrict__ bv, float* __restrict__ o)
{
  int i = blockIdx.x * 256 + threadIdx.x;
  o[i] = (i < 1024) ? bq[i] : (i < 2048 ? bk[i - 1024] : bv[i - 2048]);
}

// ---------------- LayerNorm 1: x fp32 -> h bf16 --------------------------------------
__global__ __launch_bounds__(256)
void ln1_kernel(const float* __restrict__ x, const float* __restrict__ gamma,
                bf16* __restrict__ out)
{
  __shared__ float2 red[4];
  const int row = blockIdx.x, tid = threadIdx.x;
  const float4 v = ((const float4*)(x + (size_t)row * DM))[tid];
  float s  = v.x + v.y + v.z + v.w;
  float s2 = v.x*v.x + v.y*v.y + v.z*v.z + v.w*v.w;
#pragma unroll
  for (int m = 32; m >= 1; m >>= 1) { s += __shfl_xor(s, m); s2 += __shfl_xor(s2, m); }
  if ((tid & 63) == 0) red[tid >> 6] = make_float2(s, s2);
  __syncthreads();
  float S  = red[0].x + red[1].x + red[2].x + red[3].x;
  float S2 = red[0].y + red[1].y + red[2].y + red[3].y;
  const float mean = S * (1.0f / DM);
  const float var  = S2 * (1.0f / DM) - mean * mean;
  const float rs   = rsqrtf(var + 1e-5f);
  const float4 g = ((const float4*)gamma)[tid];
  union { bf16 b[4]; uint2 u; } o;
  o.b[0] = (bf16)((v.x - mean) * rs * g.x);
  o.b[1] = (bf16)((v.y - mean) * rs * g.y);
  o.b[2] = (bf16)((v.z - mean) * rs * g.z);
  o.b[3] = (bf16)((v.w - mean) * rs * g.w);
  *(uint2*)(out + (size_t)row * DM + tid * 4) = o.u;
}

// ---------------- LayerNorm 2 (double LN): xnew fp32 -> h2 bf16 ----------------------
__global__ __launch_bounds__(256)
void ln2_kernel(const float* __restrict__ x, const float* __restrict__ gamma,
                const float* __restrict__ ffg, const float* __restrict__ ffb,
                bf16* __restrict__ out)
{
  __shared__ float2 red[4];
  const int row = blockIdx.x, tid = threadIdx.x;
  const float4 v = ((const float4*)(x + (size_t)row * DM))[tid];
  float s  = v.x + v.y + v.z + v.w;
  float s2 = v.x*v.x + v.y*v.y + v.z*v.z + v.w*v.w;
#pragma unroll
  for (int m = 32; m >= 1; m >>= 1) { s += __shfl_xor(s, m); s2 += __shfl_xor(s2, m); }
  if ((tid & 63) == 0) red[tid >> 6] = make_float2(s, s2);
  __syncthreads();
  float S  = red[0].x + red[1].x + red[2].x + red[3].x;
  float S2 = red[0].y + red[1].y + red[2].y + red[3].y;
  float mean = S * (1.0f / DM);
  float var  = S2 * (1.0f / DM) - mean * mean;
  float rs   = rsqrtf(var + 1e-5f);
  const float4 g = ((const float4*)gamma)[tid];
  float y0 = (v.x - mean) * rs * g.x;
  float y1 = (v.y - mean) * rs * g.y;
  float y2 = (v.z - mean) * rs * g.z;
  float y3 = (v.w - mean) * rs * g.w;
  __syncthreads();  // red[] reuse
  s  = y0 + y1 + y2 + y3;
  s2 = y0*y0 + y1*y1 + y2*y2 + y3*y3;
#pragma unroll
  for (int m = 32; m >= 1; m >>= 1) { s += __shfl_xor(s, m); s2 += __shfl_xor(s2, m); }
  if ((tid & 63) == 0) red[tid >> 6] = make_float2(s, s2);
  __syncthreads();
  S  = red[0].x + red[1].x + red[2].x + red[3].x;
  S2 = red[0].y + red[1].y + red[2].y + red[3].y;
  mean = S * (1.0f / DM);
  var  = S2 * (1.0f / DM) - mean * mean;
  rs   = rsqrtf(var + 1e-5f);
  const float4 a = ((const float4*)ffg)[tid];
  const float4 bb = ((const float4*)ffb)[tid];
  union { bf16 b[4]; uint2 u; } o;
  o.b[0] = (bf16)((y0 - mean) * rs * a.x + bb.x);
  o.b[1] = (bf16)((y1 - mean) * rs * a.y + bb.y);
  o.b[2] = (bf16)((y2 - mean) * rs * a.z + bb.z);
  o.b[3] = (bf16)((y3 - mean) * rs * a.w + bb.w);
  *(uint2*)(out + (size_t)row * DM + tid * 4) = o.u;
}

// ======================= 256x256 8-phase GEMM =========================================
// C[M x N] = A[M x K](bf16,lda) @ Bt[N x K]^T + bias ; EPI 0 bf16, 1 fp32+res, 2 gelu bf16
// 8 waves (2M x 4N), BK=64, LDS 128KB: per matrix 2 buf x 2 half x [128][64].
// A-half mh holds tile rows {mh*64..mh*64+63, 128+mh*64..+63} (phase-local reads).
// B-half nh holds tile rows {nh*32+q*64+0..31, q=0..3}.
// Swizzle: 16B-granule g stored from global granule g^(rho&7); reads XOR the same.

#define A_OFF(buf, mh) (((buf)*2 + (mh)) * 8192)
#define B_OFF(buf, nh) (32768 + ((buf)*2 + (nh)) * 8192)

__device__ __forceinline__ void stage_half(const bf16* __restrict__ G, long ldg,
                                           long rowBase, int k0, bf16* ldsDst,
                                           int isB, int hf, int wave, int lane)
{
#pragma unroll
  for (int l = 0; l < 2; ++l) {
    const int chunk = wave * 2 + l;
    const int rho = chunk * 8 + (lane >> 3);
    const int gsw = (lane & 7) ^ (rho & 7);
    const long grow = rowBase + (isB ? ((rho >> 5) * 64 + hf * 32 + (rho & 31))
                                     : ((rho >> 6) * 128 + hf * 64 + (rho & 63)));
    gload_lds16(&G[grow * ldg + k0 + gsw * 8], ldsDst + chunk * 512 + lane * 8);
  }
}

__device__ __forceinline__ void lda_frag(const bf16* lds, int off, int wm, int l16, int lg,
                                         bf16x8 (&dst)[4][2])
{
#pragma unroll
  for (int i = 0; i < 4; ++i) {
    const int rho = wm * 64 + i * 16 + l16;
#pragma unroll
    for (int kk = 0; kk < 2; ++kk)
      dst[i][kk] = *(const bf16x8*)&lds[off + rho * 64 + (((kk * 4 + lg) ^ (rho & 7)) << 3)];
  }
}

__device__ __forceinline__ void ldb_frag(const bf16* lds, int off, int wn, int l16, int lg,
                                         bf16x8 (&dst)[2][2])
{
#pragma unroll
  for (int j = 0; j < 2; ++j) {
    const int rho = wn * 32 + j * 16 + l16;
#pragma unroll
    for (int kk = 0; kk < 2; ++kk)
      dst[j][kk] = *(const bf16x8*)&lds[off + rho * 64 + (((kk * 4 + lg) ^ (rho & 7)) << 3)];
  }
}

__device__ __forceinline__ void mma_q(f32x4 (&acc)[8][4], bf16x8 (&af)[4][2],
                                      bf16x8 (&bq)[2][2], int mh, int nh)
{
  LGKM0();
  __builtin_amdgcn_sched_barrier(0);
  __builtin_amdgcn_s_setprio(1);
#pragma unroll
  for (int i = 0; i < 4; ++i)
#pragma unroll
    for (int j = 0; j < 2; ++j)
#pragma unroll
      for (int kk = 0; kk < 2; ++kk)
        acc[mh*4 + i][nh*2 + j] =
          __builtin_amdgcn_mfma_f32_16x16x32_bf16(af[i][kk], bq[j][kk],
                                                  acc[mh*4 + i][nh*2 + j], 0, 0, 0);
  __builtin_amdgcn_s_setprio(0);
}

template<int EPI>
__global__ __launch_bounds__(512, 2)
void gemm256(const bf16* __restrict__ A, long lda,
             const bf16* __restrict__ Bt,
             const float* __restrict__ bias,
             const float* res, long ldres,
             void* Cout, long ldc, int K)
{
  __shared__ __align__(16) bf16 lds[65536];   // 128 KB
  const int tid = threadIdx.x, lane = tid & 63, wave = tid >> 6;
  const int wm = wave >> 2, wn = wave & 3;
  const int l16 = lane & 15, lg = lane >> 4;
  const long row0 = (long)blockIdx.x * 256;
  const long col0 = (long)blockIdx.y * 256;
  const int NT = K >> 6;

  f32x4 acc[8][4] = {};
  bf16x8 af[4][2];
  bf16x8 bfr[2][2][2];   // [nh][j][kk]

  // ---- prologue: K-tile 0 fully, K-tile 1 halves Ah0,Bh0 (steady-state pattern)
  stage_half(A,  lda, row0, 0, (bf16*)lds + A_OFF(0, 0), 0, 0, wave, lane);
  stage_half(Bt, K,   col0, 0, (bf16*)lds + B_OFF(0, 0), 1, 0, wave, lane);
  stage_half(A,  lda, row0, 0, (bf16*)lds + A_OFF(0, 1), 0, 1, wave, lane);
  stage_half(Bt, K,   col0, 0, (bf16*)lds + B_OFF(0, 1), 1, 1, wave, lane);
  if (NT > 1) {
    stage_half(A,  lda, row0, 64, (bf16*)lds + A_OFF(1, 0), 0, 0, wave, lane);
    stage_half(Bt, K,   col0, 64, (bf16*)lds + B_OFF(1, 0), 1, 0, wave, lane);
    VMW4();
  } else {
    VMW0();
  }
  BAR();

  for (int t = 0; t < NT; ++t) {
    const int buf = t & 1, nb = buf ^ 1;
    const int k1 = (t + 1) << 6, k2 = (t + 2) << 6;
    const bool p1ok = (t + 1) < NT, p2ok = (t + 2) < NT;

    // ---- phase 0: quadrant (mh=0, nh=0); refill (t+1) Ah1 -> nb
    lda_frag((const bf16*)lds, A_OFF(buf, 0), wm, l16, lg, af);
    ldb_frag((const bf16*)lds, B_OFF(buf, 0), wn, l16, lg, bfr[0]);
    if (p1ok) stage_half(A, lda, row0, k1, (bf16*)lds + A_OFF(nb, 1), 0, 1, wave, lane);
    BAR();
    mma_q(acc, af, bfr[0], 0, 0);
    BAR();

    // ---- phase 1: (0,1); refill (t+1) Bh1 -> nb
    ldb_frag((const bf16*)lds, B_OFF(buf, 1), wn, l16, lg, bfr[1]);
    if (p1ok) stage_half(Bt, K, col0, k1, (bf16*)lds + B_OFF(nb, 1), 1, 1, wave, lane);
    BAR();
    mma_q(acc, af, bfr[1], 0, 1);
    BAR();

    // ---- phase 2: (1,0); refill (t+2) Ah0 -> buf (Ah0 free after phase 1)
    lda_frag((const bf16*)lds, A_OFF(buf, 1), wm, l16, lg, af);
    if (p2ok) stage_half(A, lda, row0, k2, (bf16*)lds + A_OFF(buf, 0), 0, 0, wave, lane);
    BAR();
    mma_q(acc, af, bfr[0], 1, 0);
    BAR();

    // ---- phase 3: (1,1); refill (t+2) Bh0 -> buf (Bh0 free after phase 2)
    if (p2ok) stage_half(Bt, K, col0, k2, (bf16*)lds + B_OFF(buf, 0), 1, 0, wave, lane);
    BAR();
    mma_q(acc, af, bfr[1], 1, 1);
    // boundary: wait next K-tile's 4 half-tiles; keep (t+2)'s 2 half-tiles in flight
    if (p2ok) { VMW4(); } else { VMW0(); }
    BAR();
  }

  // ---- epilogue
#pragma unroll
  for (int i = 0; i < 8; ++i) {
    const long m0 = row0 + wm * 128 + (i >> 2) * 64 + (i & 3) * 16 + lg * 4;
#pragma unroll
    for (int j = 0; j < 4; ++j) {
      const long n = col0 + wn * 64 + (j >> 1) * 32 + (j & 1) * 16 + l16;
      const float bv = bias[n];
#pragma unroll
      for (int r = 0; r < 4; ++r) {
        const long m = m0 + r;
        float v = acc[i][j][r] + bv;
        if constexpr (EPI == 0) {
          ((bf16*)Cout)[m * ldc + n] = (bf16)v;
        } else if constexpr (EPI == 1) {
          ((float*)Cout)[m * ldc + n] = v + res[m * ldres + n];
        } else {
          float gl = 0.5f * v * (1.0f + erff(v * 0.70710678118654752f));
          ((bf16*)Cout)[m * ldc + n] = (bf16)gl;
        }
      }
    }
  }
}

// ---------------- dilated attention: one wave per (b, g, h) --------------------------
__global__ __launch_bounds__(64)
void attn_kernel(bf16* qkv)
{
  __shared__ bf16 Plds[32 * 32];
  __shared__ bf16 vT[64 * 32];
  const int blk = blockIdx.x;
  const int h = blk & 15;
  const int g = (blk >> 4) & 63;
  const int b = blk >> 10;
  const int par = h & 1;
  const int lane = threadIdx.x;
  const int l16 = lane & 15, lg = lane >> 4;
  const long base = ((long)b * 4096 + g * 64) * NQKV;

  bf16x8 qf[2][2], kf[2][2];
#pragma unroll
  for (int mb = 0; mb < 2; ++mb) {
    const int s = par + 2 * (mb * 16 + l16);
    const bf16* qrow = qkv + base + (long)s * NQKV + h * 64;
#pragma unroll
    for (int kk = 0; kk < 2; ++kk) {
      qf[mb][kk] = *(const bf16x8*)(qrow + kk * 32 + lg * 8);
      kf[mb][kk] = *(const bf16x8*)(qrow + 1024 + kk * 32 + lg * 8);
    }
  }

#pragma unroll
  for (int it = 0; it < 4; ++it) {
    const int kr  = it * 8 + (lane >> 3);
    const int dh0 = (lane & 7) * 8;
    const int s = par + 2 * kr;
    union { uint4 u; bf16 e[8]; } vv;
    vv.u = *(const uint4*)(qkv + base + (long)s * NQKV + 2048 + h * 64 + dh0);
#pragma unroll
    for (int j = 0; j < 8; ++j)
      vT[(dh0 + j) * 32 + kr] = vv.e[j];
  }

  f32x4 sc[2][2] = {};
#pragma unroll
  for (int mb = 0; mb < 2; ++mb)
#pragma unroll
    for (int nb = 0; nb < 2; ++nb)
#pragma unroll
      for (int kk = 0; kk < 2; ++kk)
        sc[mb][nb] = __builtin_amdgcn_mfma_f32_16x16x32_bf16(qf[mb][kk], kf[nb][kk], sc[mb][nb], 0, 0, 0);

  float pr[2][2][4];
#pragma unroll
  for (int mb = 0; mb < 2; ++mb)
#pragma unroll
    for (int r = 0; r < 4; ++r) {
      float a0 = sc[mb][0][r] * 0.125f, a1 = sc[mb][1][r] * 0.125f;
      float mx = fmaxf(a0, a1);
#pragma unroll
      for (int msk = 8; msk >= 1; msk >>= 1) mx = fmaxf(mx, __shfl_xor(mx, msk));
      float e0 = expf(a0 - mx), e1 = expf(a1 - mx);
      float sm = e0 + e1;
#pragma unroll
      for (int msk = 8; msk >= 1; msk >>= 1) sm += __shfl_xor(sm, msk);
      float inv = 1.0f / sm;
      pr[mb][0][r] = e0 * inv;
      pr[mb][1][r] = e1 * inv;
    }

  __syncthreads();
#pragma unroll
  for (int mb = 0; mb < 2; ++mb)
#pragma unroll
    for (int nb = 0; nb < 2; ++nb)
#pragma unroll
      for (int r = 0; r < 4; ++r)
        Plds[(mb * 16 + lg * 4 + r) * 32 + nb * 16 + l16] = (bf16)pr[mb][nb][r];
  __syncthreads();

  bf16x8 pa[2], vb[4];
#pragma unroll
  for (int mb = 0; mb < 2; ++mb)
    pa[mb] = *(const bf16x8*)&Plds[(mb * 16 + l16) * 32 + lg * 8];
#pragma unroll
  for (int nb = 0; nb < 4; ++nb)
    vb[nb] = *(const bf16x8*)&vT[(nb * 16 + l16) * 32 + lg * 8];
  f32x4 oc[2][4] = {};
#pragma unroll
  for (int mb = 0; mb < 2; ++mb)
#pragma unroll
    for (int nb = 0; nb < 4; ++nb)
      oc[mb][nb] = __builtin_amdgcn_mfma_f32_16x16x32_bf16(pa[mb], vb[nb], oc[mb][nb], 0, 0, 0);

#pragma unroll
  for (int mb = 0; mb < 2; ++mb)
#pragma unroll
    for (int nb = 0; nb < 4; ++nb)
#pragma unroll
      for (int r = 0; r < 4; ++r) {
        const int m = mb * 16 + lg * 4 + r;
        const int s = par + 2 * m;
        qkv[base + (long)s * NQKV + h * 64 + nb * 16 + l16] = (bf16)oc[mb][nb][r];
      }
  const uint4 z = make_uint4(0, 0, 0, 0);
#pragma unroll
  for (int it = 0; it < 4; ++it) {
    const int r2 = it * 8 + (lane >> 3);
    const int s = (1 - par) + 2 * r2;
    *(uint4*)(qkv + base + (long)s * NQKV + h * 64 + (lane & 7) * 8) = z;
  }
}

// ---------------- host-side orchestration --------------------------------------------
extern "C" void kernel_launch(void* const* d_in, const int* in_sizes, int n_in,
                              void* d_out, int out_size, void* d_ws, size_t ws_size,
                              hipStream_t stream)
{
  const float* x     = (const float*)d_in[0];
  const float* gamma = (const float*)d_in[1];
  const float* wq = (const float*)d_in[2];  const float* bq = (const float*)d_in[3];
  const float* wk = (const float*)d_in[4];  const float* bk = (const float*)d_in[5];
  const float* wv = (const float*)d_in[6];  const float* bv = (const float*)d_in[7];
  const float* wo = (const float*)d_in[8];  const float* bo = (const float*)d_in[9];
  const float* ffg = (const float*)d_in[10]; const float* ffb = (const float*)d_in[11];
  const float* w1 = (const float*)d_in[12]; const float* b1 = (const float*)d_in[13];
  const float* w2 = (const float*)d_in[14]; const float* b2 = (const float*)d_in[15];

  char* p = (char*)d_ws;
  bf16* Wqkv_t = (bf16*)p; p += (size_t)NQKV * DM * 2;
  bf16* Wo_t   = (bf16*)p; p += (size_t)DM * DM * 2;
  bf16* W1_t   = (bf16*)p; p += (size_t)DFF * DM * 2;
  bf16* W2_t   = (bf16*)p; p += (size_t)DM * DFF * 2;
  float* bqkv  = (float*)p; p += (size_t)NQKV * 4;
  bf16* hbuf   = (bf16*)p; p += (size_t)NTOK * DM * 2;
  bf16* qkv    = (bf16*)p; p += (size_t)NTOK * DFF * 2;
  float* xnew  = (float*)d_out;

  dim3 b256(256);
  transpose_cvt<<<dim3(32, 32),  b256, 0, stream>>>(wq, Wqkv_t,               DM, DM);
  transpose_cvt<<<dim3(32, 32),  b256, 0, stream>>>(wk, Wqkv_t + 1024 * 1024, DM, DM);
  transpose_cvt<<<dim3(32, 32),  b256, 0, stream>>>(wv, Wqkv_t + 2048 * 1024, DM, DM);
  transpose_cvt<<<dim3(32, 32),  b256, 0, stream>>>(wo, Wo_t, DM, DM);
  transpose_cvt<<<dim3(128, 32), b256, 0, stream>>>(w1, W1_t, DM, DFF);
  transpose_cvt<<<dim3(32, 128), b256, 0, stream>>>(w2, W2_t, DFF, DM);
  concat_bias<<<12, b256, 0, stream>>>(bq, bk, bv, bqkv);

  ln1_kernel<<<NTOK, b256, 0, stream>>>(x, gamma, hbuf);

  // QKV GEMM: h @ [wq|wk|wv] -> qkv bf16 [16384][3072]
  gemm256<0><<<dim3(NTOK / 256, NQKV / 256), 512, 0, stream>>>(
      hbuf, DM, Wqkv_t, bqkv, nullptr, 0, qkv, NQKV, DM);

  attn_kernel<<<4096, dim3(64), 0, stream>>>(qkv);

  // WO GEMM + residual -> xnew fp32 (d_out)
  gemm256<1><<<dim3(NTOK / 256, DM / 256), 512, 0, stream>>>(
      qkv, NQKV, Wo_t, bo, x, DM, xnew, DM, DM);

  ln2_kernel<<<NTOK, b256, 0, stream>>>(xnew, gamma, ffg, ffb, hbuf);

  // FFN1 + GELU -> g1 bf16 [16384][4096]
  gemm256<2><<<dim3(NTOK / 256, DFF / 256), 512, 0, stream>>>(
      hbuf, DM, W1_t, b1, nullptr, 0, qkv, DFF, DM);

  // FFN2 + residual -> d_out fp32
  gemm256<1><<<dim3(NTOK / 256, DM / 256), 512, 0, stream>>>(
      qkv, DFF, W2_t, b2, xnew, DM, (float*)d_out, DM, DFF);
}

// Round 4
// 683.844 us; speedup vs baseline: 1.4031x; 1.0097x over previous
//
#include <hip/hip_runtime.h>
#include <hip/hip_bf16.h>
#include <math.h>

// Problem constants
#define NTOK 16384   // B*N = 4*4096
#define DM   1024
#define NQKV 3072
#define DFF  4096

typedef __bf16 bf16;
typedef __bf16 bf16x8 __attribute__((ext_vector_type(8)));
typedef float  f32x4  __attribute__((ext_vector_type(4)));

__device__ __forceinline__ void gload_lds16(const bf16* g, bf16* l) {
  __builtin_amdgcn_global_load_lds((const __attribute__((address_space(1))) void*)g,
                                   (__attribute__((address_space(3))) void*)l,
                                   16, 0, 0);
}

#define BAR()    asm volatile("s_barrier" ::: "memory")
#define SB0()    __builtin_amdgcn_sched_barrier(0)
#define LGKM(N)  asm volatile("s_waitcnt lgkmcnt(" #N ")" ::: "memory")
#define VMW4()   asm volatile("s_waitcnt vmcnt(4)" ::: "memory")
#define VMW0()   asm volatile("s_waitcnt vmcnt(0)" ::: "memory")

// ---------------- weight transpose + bf16 convert: src[K][N] fp32 -> dst[N][K] bf16 ----
__global__ __launch_bounds__(256)
void transpose_cvt(const float* __restrict__ src, bf16* __restrict__ dst, int K, int N)
{
  __shared__ float t[32][33];
  const int tx = threadIdx.x & 31, ty = threadIdx.x >> 5;
  const int n0 = blockIdx.x * 32, k0 = blockIdx.y * 32;
#pragma unroll
  for (int i = 0; i < 4; ++i)
    t[ty + 8*i][tx] = src[(size_t)(k0 + ty + 8*i) * N + n0 + tx];
  __syncthreads();
#pragma unroll
  for (int i = 0; i < 4; ++i)
    dst[(size_t)(n0 + ty + 8*i) * K + k0 + tx] = (bf16)t[tx][ty + 8*i];
}

__global__ void concat_bias(const float* __restrict__ bq, const float* __restrict__ bk,
                            const float* __restrict__ bv, float* __restrict__ o)
{
  int i = blockIdx.x * 256 + threadIdx.x;
  o[i] = (i < 1024) ? bq[i] : (i < 2048 ? bk[i - 1024] : bv[i - 2048]);
}

// ---------------- LayerNorm 1: x fp32 -> h bf16 --------------------------------------
__global__ __launch_bounds__(256)
void ln1_kernel(const float* __restrict__ x, const float* __restrict__ gamma,
                bf16* __restrict__ out)
{
  __shared__ float2 red[4];
  const int row = blockIdx.x, tid = threadIdx.x;
  const float4 v = ((const float4*)(x + (size_t)row * DM))[tid];
  float s  = v.x + v.y + v.z + v.w;
  float s2 = v.x*v.x + v.y*v.y + v.z*v.z + v.w*v.w;
#pragma unroll
  for (int m = 32; m >= 1; m >>= 1) { s += __shfl_xor(s, m); s2 += __shfl_xor(s2, m); }
  if ((tid & 63) == 0) red[tid >> 6] = make_float2(s, s2);
  __syncthreads();
  float S  = red[0].x + red[1].x + red[2].x + red[3].x;
  float S2 = red[0].y + red[1].y + red[2].y + red[3].y;
  const float mean = S * (1.0f / DM);
  const float var  = S2 * (1.0f / DM) - mean * mean;
  const float rs   = rsqrtf(var + 1e-5f);
  const float4 g = ((const float4*)gamma)[tid];
  union { bf16 b[4]; uint2 u; } o;
  o.b[0] = (bf16)((v.x - mean) * rs * g.x);
  o.b[1] = (bf16)((v.y - mean) * rs * g.y);
  o.b[2] = (bf16)((v.z - mean) * rs * g.z);
  o.b[3] = (bf16)((v.w - mean) * rs * g.w);
  *(uint2*)(out + (size_t)row * DM + tid * 4) = o.u;
}

// ---------------- LayerNorm 2 (double LN): xnew fp32 -> h2 bf16 ----------------------
__global__ __launch_bounds__(256)
void ln2_kernel(const float* __restrict__ x, const float* __restrict__ gamma,
                const float* __restrict__ ffg, const float* __restrict__ ffb,
                bf16* __restrict__ out)
{
  __shared__ float2 red[4];
  const int row = blockIdx.x, tid = threadIdx.x;
  const float4 v = ((const float4*)(x + (size_t)row * DM))[tid];
  float s  = v.x + v.y + v.z + v.w;
  float s2 = v.x*v.x + v.y*v.y + v.z*v.z + v.w*v.w;
#pragma unroll
  for (int m = 32; m >= 1; m >>= 1) { s += __shfl_xor(s, m); s2 += __shfl_xor(s2, m); }
  if ((tid & 63) == 0) red[tid >> 6] = make_float2(s, s2);
  __syncthreads();
  float S  = red[0].x + red[1].x + red[2].x + red[3].x;
  float S2 = red[0].y + red[1].y + red[2].y + red[3].y;
  float mean = S * (1.0f / DM);
  float var  = S2 * (1.0f / DM) - mean * mean;
  float rs   = rsqrtf(var + 1e-5f);
  const float4 g = ((const float4*)gamma)[tid];
  float y0 = (v.x - mean) * rs * g.x;
  float y1 = (v.y - mean) * rs * g.y;
  float y2 = (v.z - mean) * rs * g.z;
  float y3 = (v.w - mean) * rs * g.w;
  __syncthreads();  // red[] reuse
  s  = y0 + y1 + y2 + y3;
  s2 = y0*y0 + y1*y1 + y2*y2 + y3*y3;
#pragma unroll
  for (int m = 32; m >= 1; m >>= 1) { s += __shfl_xor(s, m); s2 += __shfl_xor(s2, m); }
  if ((tid & 63) == 0) red[tid >> 6] = make_float2(s, s2);
  __syncthreads();
  S  = red[0].x + red[1].x + red[2].x + red[3].x;
  S2 = red[0].y + red[1].y + red[2].y + red[3].y;
  mean = S * (1.0f / DM);
  var  = S2 * (1.0f / DM) - mean * mean;
  rs   = rsqrtf(var + 1e-5f);
  const float4 a = ((const float4*)ffg)[tid];
  const float4 bb = ((const float4*)ffb)[tid];
  union { bf16 b[4]; uint2 u; } o;
  o.b[0] = (bf16)((y0 - mean) * rs * a.x + bb.x);
  o.b[1] = (bf16)((y1 - mean) * rs * a.y + bb.y);
  o.b[2] = (bf16)((y2 - mean) * rs * a.z + bb.z);
  o.b[3] = (bf16)((y3 - mean) * rs * a.w + bb.w);
  *(uint2*)(out + (size_t)row * DM + tid * 4) = o.u;
}

// ======================= 256x256 4-phase/K-tile GEMM ==================================
// C[M x N] = A[M x K](bf16,lda) @ Bt[N x K]^T + bias ; EPI 0 bf16, 1 fp32+res, 2 gelu bf16
// 8 waves (2M x 4N), BK=64, LDS 128KB: A halves low (imm-foldable), B halves high.
// All addressing hoisted: staging = u32 byte offsets += 128; frag offsets precomputed.

#define A_OFF(buf, mh) (((buf)*2 + (mh)) * 8192)
#define B_OFF(buf, nh) (32768 + ((buf)*2 + (nh)) * 8192)

__device__ __forceinline__ void mmaq(f32x4 (&acc)[8][4], bf16x8 (&a)[4][2],
                                     bf16x8 (&b)[2][2], int mh, int nh)
{
  __builtin_amdgcn_s_setprio(1);
#pragma unroll
  for (int i = 0; i < 4; ++i)
#pragma unroll
    for (int j = 0; j < 2; ++j)
#pragma unroll
      for (int kk = 0; kk < 2; ++kk)
        acc[mh*4 + i][nh*2 + j] =
          __builtin_amdgcn_mfma_f32_16x16x32_bf16(a[i][kk], b[j][kk],
                                                  acc[mh*4 + i][nh*2 + j], 0, 0, 0);
  __builtin_amdgcn_s_setprio(0);
}

template<int EPI>
__global__ __launch_bounds__(512, 2)
void gemm256(const bf16* __restrict__ A, int lda,
             const bf16* __restrict__ Bt,
             const float* __restrict__ bias,
             const float* res, int ldres,
             void* Cout, int ldc, int K, int nblk)
{
  __shared__ __align__(16) bf16 lds[65536];   // 128 KB
  const int tid = threadIdx.x, lane = tid & 63, wave = tid >> 6;
  const int wm = wave >> 2, wn = wave & 3;
  const int l16 = lane & 15, lg = lane >> 4;

  // XCD-aware swizzle (nblk % 8 == 0 for all our grids); M always 16384 -> 64 row blocks
  int id = blockIdx.x;
  id = (id & 7) * (nblk >> 3) + (id >> 3);
  const int row0 = (id & 63) << 8;
  const int col0 = (id >> 6) << 8;
  const int NT = K >> 6;

  // ---- staging byte offsets (advance += 128 per use) -------------------------------
  const char* Ab = (const char*)A;
  const char* Bb = (const char*)Bt;
  unsigned oA[2][2], oB[2][2];   // [hf][l]
  {
    const int lr = lane >> 3, lc = lane & 7;
#pragma unroll
    for (int l = 0; l < 2; ++l) {
      const int rho = (wave * 2 + l) * 8 + lr;
      const int gc = ((lc ^ (rho & 7)) << 3);
#pragma unroll
      for (int hf = 0; hf < 2; ++hf) {
        const int ga = (rho >> 6) * 128 + hf * 64 + (rho & 63);
        const int gb = (rho >> 5) * 64 + hf * 32 + (rho & 31);
        oA[hf][l] = (unsigned)(((row0 + ga) * lda + gc) * 2);
        oB[hf][l] = (unsigned)(((col0 + gb) * K + gc) * 2);
      }
    }
  }
  const int so = wave * 1024 + lane * 8;  // LDS element offset of this lane's DMA slot

#define STAGE_A(hf, OFF) do { \
    gload_lds16((const bf16*)(Ab + oA[hf][0]), (bf16*)lds + (OFF) + so); \
    gload_lds16((const bf16*)(Ab + oA[hf][1]), (bf16*)lds + (OFF) + so + 512); \
    oA[hf][0] += 128; oA[hf][1] += 128; } while (0)
#define STAGE_B(hf, OFF) do { \
    gload_lds16((const bf16*)(Bb + oB[hf][0]), (bf16*)lds + (OFF) + so); \
    gload_lds16((const bf16*)(Bb + oB[hf][1]), (bf16*)lds + (OFF) + so + 512); \
    oB[hf][0] += 128; oB[hf][1] += 128; } while (0)

  // ---- frag LDS element offsets (iteration-invariant, swizzle baked in) ------------
  int aoff[4][2], boff[2][2];
#pragma unroll
  for (int i = 0; i < 4; ++i) {
    const int rho = wm * 64 + i * 16 + l16;
#pragma unroll
    for (int kk = 0; kk < 2; ++kk)
      aoff[i][kk] = rho * 64 + (((kk * 4 + lg) ^ (rho & 7)) << 3);
  }
#pragma unroll
  for (int j = 0; j < 2; ++j) {
    const int rho = wn * 32 + j * 16 + l16;
#pragma unroll
    for (int kk = 0; kk < 2; ++kk)
      boff[j][kk] = rho * 64 + (((kk * 4 + lg) ^ (rho & 7)) << 3);
  }

#define LDAF(OFF) do { \
    af[0][0] = *(const bf16x8*)&lds[(OFF) + aoff[0][0]]; \
    af[0][1] = *(const bf16x8*)&lds[(OFF) + aoff[0][1]]; \
    af[1][0] = *(const bf16x8*)&lds[(OFF) + aoff[1][0]]; \
    af[1][1] = *(const bf16x8*)&lds[(OFF) + aoff[1][1]]; \
    af[2][0] = *(const bf16x8*)&lds[(OFF) + aoff[2][0]]; \
    af[2][1] = *(const bf16x8*)&lds[(OFF) + aoff[2][1]]; \
    af[3][0] = *(const bf16x8*)&lds[(OFF) + aoff[3][0]]; \
    af[3][1] = *(const bf16x8*)&lds[(OFF) + aoff[3][1]]; } while (0)
#define LDBF(dst, OFF) do { \
    dst[0][0] = *(const bf16x8*)&lds[(OFF) + boff[0][0]]; \
    dst[0][1] = *(const bf16x8*)&lds[(OFF) + boff[0][1]]; \
    dst[1][0] = *(const bf16x8*)&lds[(OFF) + boff[1][0]]; \
    dst[1][1] = *(const bf16x8*)&lds[(OFF) + boff[1][1]]; } while (0)

  f32x4 acc[8][4] = {};
  bf16x8 af[4][2], b0f[2][2], b1f[2][2];

  // ---- prologue: tile0 all 4 halves; tile1 halves A0,B0; keep last 4 loads in flight
  STAGE_A(0, A_OFF(0, 0)); STAGE_B(0, B_OFF(0, 0));
  STAGE_A(1, A_OFF(0, 1)); STAGE_B(1, B_OFF(0, 1));
  if (NT > 1) { STAGE_A(0, A_OFF(1, 0)); STAGE_B(0, B_OFF(1, 0)); VMW4(); }
  else        { VMW0(); }
  BAR();

  // Phase ledger (per tile t, buf=t&1, nb=buf^1):
  //  ph0: read A0,B0,B1 frags (16 ds_reads); stage Ah1(t+1)->nb; lgkm(4); Q00; BAR
  //  ph1: stage Bh1(t+1)->nb; lgkm(0); Q01; read A1 frags (drain over BAR); BAR
  //  ph2: stage Ah0(t+2)->buf; lgkm(0); Q10; BAR
  //  ph3: stage Bh0(t+2)->buf; Q11; vmcnt(4|0); BAR
  // Safety: every LDS region's reads drain at a counted lgkm >=1 barrier before its
  // re-stage; cross-wave DMA visibility only assumed at tile boundaries (vmcnt+BAR,
  // BAR carries a "memory" clobber so no ds_read hoists between vmcnt and barrier).
#define TILE_BODY(BUF) do { \
    const bool p1 = (t + 1) < NT, p2 = (t + 2) < NT; \
    LDAF(A_OFF(BUF, 0)); \
    LDBF(b0f, B_OFF(BUF, 0)); \
    LDBF(b1f, B_OFF(BUF, 1)); \
    if (p1) STAGE_A(1, A_OFF(BUF ^ 1, 1)); \
    LGKM(4); SB0(); \
    mmaq(acc, af, b0f, 0, 0); \
    BAR(); \
    if (p1) STAGE_B(1, B_OFF(BUF ^ 1, 1)); \
    LGKM(0); SB0(); \
    mmaq(acc, af, b1f, 0, 1); \
    LDAF(A_OFF(BUF, 1)); \
    BAR(); \
    if (p2) STAGE_A(0, A_OFF(BUF, 0)); \
    LGKM(0); SB0(); \
    mmaq(acc, af, b0f, 1, 0); \
    BAR(); \
    if (p2) STAGE_B(0, B_OFF(BUF, 0)); \
    mmaq(acc, af, b1f, 1, 1); \
    if (p2) { VMW4(); } else { VMW0(); } \
    BAR(); } while (0)

  for (int t = 0; t < NT; ++t) {   // NT always even; t advances once here + once below
    TILE_BODY(0);
    ++t;
    TILE_BODY(1);
  }

  // ---- epilogue
#pragma unroll
  for (int i = 0; i < 8; ++i) {
    const int m0 = row0 + wm * 128 + (i >> 2) * 64 + (i & 3) * 16 + lg * 4;
#pragma unroll
    for (int j = 0; j < 4; ++j) {
      const int n = col0 + wn * 64 + (j >> 1) * 32 + (j & 1) * 16 + l16;
      const float bv = bias[n];
#pragma unroll
      for (int r = 0; r < 4; ++r) {
        const long m = m0 + r;
        float v = acc[i][j][r] + bv;
        if constexpr (EPI == 0) {
          ((bf16*)Cout)[m * ldc + n] = (bf16)v;
        } else if constexpr (EPI == 1) {
          ((float*)Cout)[m * ldc + n] = v + res[m * ldres + n];
        } else {
          float gl = 0.5f * v * (1.0f + erff(v * 0.70710678118654752f));
          ((bf16*)Cout)[m * ldc + n] = (bf16)gl;
        }
      }
    }
  }
}

// ---------------- dilated attention: one wave per (b, g, h) --------------------------
__global__ __launch_bounds__(64)
void attn_kernel(bf16* qkv)
{
  __shared__ bf16 Plds[32 * 32];
  __shared__ bf16 vT[64 * 32];
  const int blk = blockIdx.x;
  const int h = blk & 15;
  const int g = (blk >> 4) & 63;
  const int b = blk >> 10;
  const int par = h & 1;
  const int lane = threadIdx.x;
  const int l16 = lane & 15, lg = lane >> 4;
  const long base = ((long)b * 4096 + g * 64) * NQKV;

  bf16x8 qf[2][2], kf[2][2];
#pragma unroll
  for (int mb = 0; mb < 2; ++mb) {
    const int s = par + 2 * (mb * 16 + l16);
    const bf16* qrow = qkv + base + (long)s * NQKV + h * 64;
#pragma unroll
    for (int kk = 0; kk < 2; ++kk) {
      qf[mb][kk] = *(const bf16x8*)(qrow + kk * 32 + lg * 8);
      kf[mb][kk] = *(const bf16x8*)(qrow + 1024 + kk * 32 + lg * 8);
    }
  }

#pragma unroll
  for (int it = 0; it < 4; ++it) {
    const int kr  = it * 8 + (lane >> 3);
    const int dh0 = (lane & 7) * 8;
    const int s = par + 2 * kr;
    union { uint4 u; bf16 e[8]; } vv;
    vv.u = *(const uint4*)(qkv + base + (long)s * NQKV + 2048 + h * 64 + dh0);
#pragma unroll
    for (int j = 0; j < 8; ++j)
      vT[(dh0 + j) * 32 + kr] = vv.e[j];
  }

  f32x4 sc[2][2] = {};
#pragma unroll
  for (int mb = 0; mb < 2; ++mb)
#pragma unroll
    for (int nb = 0; nb < 2; ++nb)
#pragma unroll
      for (int kk = 0; kk < 2; ++kk)
        sc[mb][nb] = __builtin_amdgcn_mfma_f32_16x16x32_bf16(qf[mb][kk], kf[nb][kk], sc[mb][nb], 0, 0, 0);

  float pr[2][2][4];
#pragma unroll
  for (int mb = 0; mb < 2; ++mb)
#pragma unroll
    for (int r = 0; r < 4; ++r) {
      float a0 = sc[mb][0][r] * 0.125f, a1 = sc[mb][1][r] * 0.125f;
      float mx = fmaxf(a0, a1);
#pragma unroll
      for (int msk = 8; msk >= 1; msk >>= 1) mx = fmaxf(mx, __shfl_xor(mx, msk));
      float e0 = expf(a0 - mx), e1 = expf(a1 - mx);
      float sm = e0 + e1;
#pragma unroll
      for (int msk = 8; msk >= 1; msk >>= 1) sm += __shfl_xor(sm, msk);
      float inv = 1.0f / sm;
      pr[mb][0][r] = e0 * inv;
      pr[mb][1][r] = e1 * inv;
    }

  __syncthreads();
#pragma unroll
  for (int mb = 0; mb < 2; ++mb)
#pragma unroll
    for (int nb = 0; nb < 2; ++nb)
#pragma unroll
      for (int r = 0; r < 4; ++r)
        Plds[(mb * 16 + lg * 4 + r) * 32 + nb * 16 + l16] = (bf16)pr[mb][nb][r];
  __syncthreads();

  bf16x8 pa[2], vb[4];
#pragma unroll
  for (int mb = 0; mb < 2; ++mb)
    pa[mb] = *(const bf16x8*)&Plds[(mb * 16 + l16) * 32 + lg * 8];
#pragma unroll
  for (int nb = 0; nb < 4; ++nb)
    vb[nb] = *(const bf16x8*)&vT[(nb * 16 + l16) * 32 + lg * 8];
  f32x4 oc[2][4] = {};
#pragma unroll
  for (int mb = 0; mb < 2; ++mb)
#pragma unroll
    for (int nb = 0; nb < 4; ++nb)
      oc[mb][nb] = __builtin_amdgcn_mfma_f32_16x16x32_bf16(pa[mb], vb[nb], oc[mb][nb], 0, 0, 0);

#pragma unroll
  for (int mb = 0; mb < 2; ++mb)
#pragma unroll
    for (int nb = 0; nb < 4; ++nb)
#pragma unroll
      for (int r = 0; r < 4; ++r) {
        const int m = mb * 16 + lg * 4 + r;
        const int s = par + 2 * m;
        qkv[base + (long)s * NQKV + h * 64 + nb * 16 + l16] = (bf16)oc[mb][nb][r];
      }
  const uint4 z = make_uint4(0, 0, 0, 0);
#pragma unroll
  for (int it = 0; it < 4; ++it) {
    const int r2 = it * 8 + (lane >> 3);
    const int s = (1 - par) + 2 * r2;
    *(uint4*)(qkv + base + (long)s * NQKV + h * 64 + (lane & 7) * 8) = z;
  }
}

// ---------------- host-side orchestration --------------------------------------------
extern "C" void kernel_launch(void* const* d_in, const int* in_sizes, int n_in,
                              void* d_out, int out_size, void* d_ws, size_t ws_size,
                              hipStream_t stream)
{
  const float* x     = (const float*)d_in[0];
  const float* gamma = (const float*)d_in[1];
  const float* wq = (const float*)d_in[2];  const float* bq = (const float*)d_in[3];
  const float* wk = (const float*)d_in[4];  const float* bk = (const float*)d_in[5];
  const float* wv = (const float*)d_in[6];  const float* bv = (const float*)d_in[7];
  const float* wo = (const float*)d_in[8];  const float* bo = (const float*)d_in[9];
  const float* ffg = (const float*)d_in[10]; const float* ffb = (const float*)d_in[11];
  const float* w1 = (const float*)d_in[12]; const float* b1 = (const float*)d_in[13];
  const float* w2 = (const float*)d_in[14]; const float* b2 = (const float*)d_in[15];

  char* p = (char*)d_ws;
  bf16* Wqkv_t = (bf16*)p; p += (size_t)NQKV * DM * 2;
  bf16* Wo_t   = (bf16*)p; p += (size_t)DM * DM * 2;
  bf16* W1_t   = (bf16*)p; p += (size_t)DFF * DM * 2;
  bf16* W2_t   = (bf16*)p; p += (size_t)DM * DFF * 2;
  float* bqkv  = (float*)p; p += (size_t)NQKV * 4;
  bf16* hbuf   = (bf16*)p; p += (size_t)NTOK * DM * 2;
  bf16* qkv    = (bf16*)p; p += (size_t)NTOK * DFF * 2;
  float* xnew  = (float*)d_out;

  dim3 b256(256);
  transpose_cvt<<<dim3(32, 32),  b256, 0, stream>>>(wq, Wqkv_t,               DM, DM);
  transpose_cvt<<<dim3(32, 32),  b256, 0, stream>>>(wk, Wqkv_t + 1024 * 1024, DM, DM);
  transpose_cvt<<<dim3(32, 32),  b256, 0, stream>>>(wv, Wqkv_t + 2048 * 1024, DM, DM);
  transpose_cvt<<<dim3(32, 32),  b256, 0, stream>>>(wo, Wo_t, DM, DM);
  transpose_cvt<<<dim3(128, 32), b256, 0, stream>>>(w1, W1_t, DM, DFF);
  transpose_cvt<<<dim3(32, 128), b256, 0, stream>>>(w2, W2_t, DFF, DM);
  concat_bias<<<12, b256, 0, stream>>>(bq, bk, bv, bqkv);

  ln1_kernel<<<NTOK, b256, 0, stream>>>(x, gamma, hbuf);

  // QKV GEMM: h @ [wq|wk|wv] -> qkv bf16 [16384][3072]
  gemm256<0><<<dim3(768), 512, 0, stream>>>(
      hbuf, DM, Wqkv_t, bqkv, nullptr, 0, qkv, NQKV, DM, 768);

  attn_kernel<<<4096, dim3(64), 0, stream>>>(qkv);

  // WO GEMM + residual -> xnew fp32 (d_out)
  gemm256<1><<<dim3(256), 512, 0, stream>>>(
      qkv, NQKV, Wo_t, bo, x, DM, xnew, DM, DM, 256);

  ln2_kernel<<<NTOK, b256, 0, stream>>>(xnew, gamma, ffg, ffb, hbuf);

  // FFN1 + GELU -> g1 bf16 [16384][4096]
  gemm256<2><<<dim3(1024), 512, 0, stream>>>(
      hbuf, DM, W1_t, b1, nullptr, 0, qkv, DFF, DM, 1024);

  // FFN2 + residual -> d_out fp32
  gemm256<1><<<dim3(256), 512, 0, stream>>>(
      qkv, DFF, W2_t, b2, xnew, DM, (float*)d_out, DM, DFF, 256);
}